// Round 2
// baseline (190.587 us; speedup 1.0000x reference)
//
#include <hip/hip_runtime.h>

// IoU mean over B=1e6 x NBOX=6 midpoint-format box pairs, sentinel-masked.
// Streaming reduction: 192 MB logical in, 1 float out.
// R0: 1024 blk, MLP=2              -> iou_partial 66.6 us, 1.44 TB/s HBM
// R1: 2048 blk (100% waves), MLP=8 -> 68.0 us. Wall insensitive to occ/MLP.
// R3: nontemporal loads (dwordx4 nt) -> iou_partial < 56 us (left top-5);
//     harness fills sustain 6.8 TB/s -> old wall was cache-allocation
//     policy, not DRAM. Total now dominated by harness restore traffic.
// R4: exact-cover grid (1953 blk x 256 x 12 pairs), unroll-6, split
//     accumulators -> 194 -> 190 us total.
// R5: replace IEEE fdiv (v_div_scale/fmas/fixup, ~10 VALU + long chain per
//     pair) with v_rcp_f32 + mul (~1e-7 rel err vs 1.3e-3 threshold).
//     Last VALU lever; if neutral, kernel is at streaming equilibrium.
// R6: identical resubmit — container died twice, no counters.
// R7 (this round): identical resubmit — broker capacity timeout, still no
//     counters. Holding the verified R5 state until a bench lands; blind
//     edits would make the next measurement unattributable.

#define BLOCKS 1953
#define THREADS 256

typedef float vfloat4 __attribute__((ext_vector_type(4)));

__device__ __forceinline__ vfloat4 nt_load4(const float4* p) {
    return __builtin_nontemporal_load((const vfloat4*)p);
}

__device__ __forceinline__ void iou_accum(vfloat4 p, vfloat4 t,
                                          float& s_iou, float& s_cnt) {
    // valid iff truth row is not the sentinel [-1,-1,-1,-1]; branchless mask
    float v = (t.x == -1.0f && t.y == -1.0f &&
               t.z == -1.0f && t.w == -1.0f) ? 0.0f : 1.0f;

    float p_x1 = p.x - p.z * 0.5f;
    float p_y1 = p.y - p.w * 0.5f;
    float p_x2 = p.x + p.z * 0.5f;
    float p_y2 = p.y + p.w * 0.5f;
    float t_x1 = t.x - t.z * 0.5f;
    float t_y1 = t.y - t.w * 0.5f;
    float t_x2 = t.x + t.z * 0.5f;
    float t_y2 = t.y + t.w * 0.5f;

    float x1 = fmaxf(p_x1, t_x1);
    float y1 = fmaxf(p_y1, t_y1);
    float x2 = fminf(p_x2, t_x2);
    float y2 = fminf(p_y2, t_y2);

    float inter  = fmaxf(x2 - x1, 0.0f) * fmaxf(y2 - y1, 0.0f);
    float area_p = fabsf((p_x2 - p_x1) * (p_y2 - p_y1));
    float area_t = fabsf((t_x2 - t_x1) * (t_y2 - t_y1));

    // fast reciprocal: v_rcp_f32 (rel err ~1e-7) instead of IEEE fdiv
    float denom = area_p + area_t - inter + 1e-6f;
    s_iou += v * inter * __builtin_amdgcn_rcpf(denom);
    s_cnt += v;
}

__global__ __launch_bounds__(THREADS) void iou_partial(
    const float4* __restrict__ pred,
    const float4* __restrict__ truth,
    float* __restrict__ partials,   // [BLOCKS][2]: {sum_iou, sum_valid}
    int n)                          // number of (b,box) pairs
{
    int tid = blockIdx.x * THREADS + threadIdx.x;
    const int stride = BLOCKS * THREADS;

    // two independent accumulator pairs to break the rcp->add serial chain
    float s_iou0 = 0.0f, s_cnt0 = 0.0f;
    float s_iou1 = 0.0f, s_cnt1 = 0.0f;

    int i = tid;
    // unroll x6: 12 independent nt loads in flight before any compute
    for (; i + 5 * stride < n; i += 6 * stride) {
        vfloat4 p0 = nt_load4(&pred[i]);
        vfloat4 p1 = nt_load4(&pred[i + stride]);
        vfloat4 p2 = nt_load4(&pred[i + 2 * stride]);
        vfloat4 p3 = nt_load4(&pred[i + 3 * stride]);
        vfloat4 p4 = nt_load4(&pred[i + 4 * stride]);
        vfloat4 p5 = nt_load4(&pred[i + 5 * stride]);
        vfloat4 t0 = nt_load4(&truth[i]);
        vfloat4 t1 = nt_load4(&truth[i + stride]);
        vfloat4 t2 = nt_load4(&truth[i + 2 * stride]);
        vfloat4 t3 = nt_load4(&truth[i + 3 * stride]);
        vfloat4 t4 = nt_load4(&truth[i + 4 * stride]);
        vfloat4 t5 = nt_load4(&truth[i + 5 * stride]);
        iou_accum(p0, t0, s_iou0, s_cnt0);
        iou_accum(p1, t1, s_iou1, s_cnt1);
        iou_accum(p2, t2, s_iou0, s_cnt0);
        iou_accum(p3, t3, s_iou1, s_cnt1);
        iou_accum(p4, t4, s_iou0, s_cnt0);
        iou_accum(p5, t5, s_iou1, s_cnt1);
    }
    for (; i < n; i += stride) {
        vfloat4 p = nt_load4(&pred[i]);
        vfloat4 t = nt_load4(&truth[i]);
        iou_accum(p, t, s_iou0, s_cnt0);
    }

    float s_iou = s_iou0 + s_iou1;
    float s_cnt = s_cnt0 + s_cnt1;

    // wave (64-lane) shuffle reduction
    for (int off = 32; off > 0; off >>= 1) {
        s_iou += __shfl_down(s_iou, off, 64);
        s_cnt += __shfl_down(s_cnt, off, 64);
    }

    __shared__ float lds_iou[THREADS / 64];
    __shared__ float lds_cnt[THREADS / 64];
    int lane = threadIdx.x & 63;
    int wave = threadIdx.x >> 6;
    if (lane == 0) {
        lds_iou[wave] = s_iou;
        lds_cnt[wave] = s_cnt;
    }
    __syncthreads();

    if (threadIdx.x == 0) {
        float a = 0.0f, b = 0.0f;
        #pragma unroll
        for (int w = 0; w < THREADS / 64; ++w) {
            a += lds_iou[w];
            b += lds_cnt[w];
        }
        partials[2 * blockIdx.x]     = a;
        partials[2 * blockIdx.x + 1] = b;
    }
}

__global__ __launch_bounds__(THREADS) void iou_finalize(
    const float* __restrict__ partials, int nblocks, float* __restrict__ out)
{
    float s_iou = 0.0f;
    float s_cnt = 0.0f;
    for (int i = threadIdx.x; i < nblocks; i += blockDim.x) {
        s_iou += partials[2 * i];
        s_cnt += partials[2 * i + 1];
    }
    for (int off = 32; off > 0; off >>= 1) {
        s_iou += __shfl_down(s_iou, off, 64);
        s_cnt += __shfl_down(s_cnt, off, 64);
    }
    __shared__ float lds_iou[THREADS / 64];
    __shared__ float lds_cnt[THREADS / 64];
    int lane = threadIdx.x & 63;
    int wave = threadIdx.x >> 6;
    if (lane == 0) {
        lds_iou[wave] = s_iou;
        lds_cnt[wave] = s_cnt;
    }
    __syncthreads();
    if (threadIdx.x == 0) {
        float a = 0.0f, b = 0.0f;
        #pragma unroll
        for (int w = 0; w < THREADS / 64; ++w) {
            a += lds_iou[w];
            b += lds_cnt[w];
        }
        // final divide runs once; keep it exact
        out[0] = (b > 0.0f) ? (a / fmaxf(b, 1.0f)) : 0.0f;
    }
}

extern "C" void kernel_launch(void* const* d_in, const int* in_sizes, int n_in,
                              void* d_out, int out_size, void* d_ws, size_t ws_size,
                              hipStream_t stream) {
    const float4* pred  = (const float4*)d_in[0];
    const float4* truth = (const float4*)d_in[1];
    float* out = (float*)d_out;
    float* partials = (float*)d_ws;   // BLOCKS*2 floats, overwritten every call

    int n_pairs = in_sizes[0] / 4;    // B * NBOX

    iou_partial<<<BLOCKS, THREADS, 0, stream>>>(pred, truth, partials, n_pairs);
    iou_finalize<<<1, THREADS, 0, stream>>>(partials, BLOCKS, out);
}

// Round 3
// 188.762 us; speedup vs baseline: 1.0097x; 1.0097x over previous
//
#include <hip/hip_runtime.h>

// IoU mean over B=1e6 x NBOX=6 midpoint-format box pairs, sentinel-masked.
// Streaming reduction: 192 MB logical in, 1 float out.
// R0: 1024 blk, MLP=2              -> iou_partial 66.6 us, 1.44 TB/s HBM
// R1: 2048 blk (100% waves), MLP=8 -> 68.0 us. Wall insensitive to occ/MLP.
// R3: nontemporal loads (dwordx4 nt) -> iou_partial < 56 us (left top-5);
//     harness fills sustain 6.8 TB/s -> old wall was cache-allocation
//     policy, not DRAM. Total now dominated by harness restore traffic.
// R4: exact-cover grid (1953 blk x 256 x 12 pairs), unroll-6, split
//     accumulators -> 194 -> 190 us total.
// R5: rcp_f32 instead of IEEE fdiv. Verified 189.7 us.
// R6/R7: infra failures (container crash, broker timeout). No data.
// R8: clean re-baseline: 190.6 us total, top-5 all harness fills at
//     6.65-6.74 TB/s (384 MB writes). Back-solve: iou_partial ~55 us
//     = ~3.5 TB/s read, ~52% of demonstrated sustainable BW. MLP and
//     VALU arithmetic both rule out latency/compute -> remaining theory
//     is DRAM page locality: grid-stride presents scattered 4 KB
//     fragments at 8 MB strides.
// R9 (this round): contiguous per-block chunking. 1024 blocks, each owns
//     a contiguous ~5860-pair span of pred+truth and streams it
//     sequentially (unroll-8, 4 KB/step/array per block). Predict
//     iou_partial 55 -> 35-40 us, total -> ~170-178 us. If neutral,
//     layout is moot under channel interleave -> probe nt policy next.

#define BLOCKS 1024
#define THREADS 256
#define UNROLL 8

typedef float vfloat4 __attribute__((ext_vector_type(4)));

__device__ __forceinline__ vfloat4 nt_load4(const float4* p) {
    return __builtin_nontemporal_load((const vfloat4*)p);
}

__device__ __forceinline__ void iou_accum(vfloat4 p, vfloat4 t,
                                          float& s_iou, float& s_cnt) {
    // valid iff truth row is not the sentinel [-1,-1,-1,-1]; branchless mask
    float v = (t.x == -1.0f && t.y == -1.0f &&
               t.z == -1.0f && t.w == -1.0f) ? 0.0f : 1.0f;

    float p_x1 = p.x - p.z * 0.5f;
    float p_y1 = p.y - p.w * 0.5f;
    float p_x2 = p.x + p.z * 0.5f;
    float p_y2 = p.y + p.w * 0.5f;
    float t_x1 = t.x - t.z * 0.5f;
    float t_y1 = t.y - t.w * 0.5f;
    float t_x2 = t.x + t.z * 0.5f;
    float t_y2 = t.y + t.w * 0.5f;

    float x1 = fmaxf(p_x1, t_x1);
    float y1 = fmaxf(p_y1, t_y1);
    float x2 = fminf(p_x2, t_x2);
    float y2 = fminf(p_y2, t_y2);

    float inter  = fmaxf(x2 - x1, 0.0f) * fmaxf(y2 - y1, 0.0f);
    float area_p = fabsf((p_x2 - p_x1) * (p_y2 - p_y1));
    float area_t = fabsf((t_x2 - t_x1) * (t_y2 - t_y1));

    // fast reciprocal: v_rcp_f32 (rel err ~1e-7) instead of IEEE fdiv
    float denom = area_p + area_t - inter + 1e-6f;
    s_iou += v * inter * __builtin_amdgcn_rcpf(denom);
    s_cnt += v;
}

__global__ __launch_bounds__(THREADS) void iou_partial(
    const float4* __restrict__ pred,
    const float4* __restrict__ truth,
    float* __restrict__ partials,   // [BLOCKS][2]: {sum_iou, sum_valid}
    int n)                          // number of (b,box) pairs
{
    // contiguous per-block chunk: block b streams [base, end) sequentially
    const int chunk = (n + BLOCKS - 1) / BLOCKS;
    const int base  = blockIdx.x * chunk;
    const int end   = min(base + chunk, n);

    // two independent accumulator pairs to break the rcp->add serial chain
    float s_iou0 = 0.0f, s_cnt0 = 0.0f;
    float s_iou1 = 0.0f, s_cnt1 = 0.0f;

    int i = base + threadIdx.x;
    // unroll x8: 16 independent nt loads in flight; consecutive steps are
    // 4 KB apart -> each block is one long sequential stream per array
    for (; i + (UNROLL - 1) * THREADS < end; i += UNROLL * THREADS) {
        vfloat4 p0 = nt_load4(&pred[i]);
        vfloat4 p1 = nt_load4(&pred[i + 1 * THREADS]);
        vfloat4 p2 = nt_load4(&pred[i + 2 * THREADS]);
        vfloat4 p3 = nt_load4(&pred[i + 3 * THREADS]);
        vfloat4 p4 = nt_load4(&pred[i + 4 * THREADS]);
        vfloat4 p5 = nt_load4(&pred[i + 5 * THREADS]);
        vfloat4 p6 = nt_load4(&pred[i + 6 * THREADS]);
        vfloat4 p7 = nt_load4(&pred[i + 7 * THREADS]);
        vfloat4 t0 = nt_load4(&truth[i]);
        vfloat4 t1 = nt_load4(&truth[i + 1 * THREADS]);
        vfloat4 t2 = nt_load4(&truth[i + 2 * THREADS]);
        vfloat4 t3 = nt_load4(&truth[i + 3 * THREADS]);
        vfloat4 t4 = nt_load4(&truth[i + 4 * THREADS]);
        vfloat4 t5 = nt_load4(&truth[i + 5 * THREADS]);
        vfloat4 t6 = nt_load4(&truth[i + 6 * THREADS]);
        vfloat4 t7 = nt_load4(&truth[i + 7 * THREADS]);
        iou_accum(p0, t0, s_iou0, s_cnt0);
        iou_accum(p1, t1, s_iou1, s_cnt1);
        iou_accum(p2, t2, s_iou0, s_cnt0);
        iou_accum(p3, t3, s_iou1, s_cnt1);
        iou_accum(p4, t4, s_iou0, s_cnt0);
        iou_accum(p5, t5, s_iou1, s_cnt1);
        iou_accum(p6, t6, s_iou0, s_cnt0);
        iou_accum(p7, t7, s_iou1, s_cnt1);
    }
    for (; i < end; i += THREADS) {
        vfloat4 p = nt_load4(&pred[i]);
        vfloat4 t = nt_load4(&truth[i]);
        iou_accum(p, t, s_iou0, s_cnt0);
    }

    float s_iou = s_iou0 + s_iou1;
    float s_cnt = s_cnt0 + s_cnt1;

    // wave (64-lane) shuffle reduction
    for (int off = 32; off > 0; off >>= 1) {
        s_iou += __shfl_down(s_iou, off, 64);
        s_cnt += __shfl_down(s_cnt, off, 64);
    }

    __shared__ float lds_iou[THREADS / 64];
    __shared__ float lds_cnt[THREADS / 64];
    int lane = threadIdx.x & 63;
    int wave = threadIdx.x >> 6;
    if (lane == 0) {
        lds_iou[wave] = s_iou;
        lds_cnt[wave] = s_cnt;
    }
    __syncthreads();

    if (threadIdx.x == 0) {
        float a = 0.0f, b = 0.0f;
        #pragma unroll
        for (int w = 0; w < THREADS / 64; ++w) {
            a += lds_iou[w];
            b += lds_cnt[w];
        }
        partials[2 * blockIdx.x]     = a;
        partials[2 * blockIdx.x + 1] = b;
    }
}

__global__ __launch_bounds__(THREADS) void iou_finalize(
    const float* __restrict__ partials, int nblocks, float* __restrict__ out)
{
    float s_iou = 0.0f;
    float s_cnt = 0.0f;
    for (int i = threadIdx.x; i < nblocks; i += blockDim.x) {
        s_iou += partials[2 * i];
        s_cnt += partials[2 * i + 1];
    }
    for (int off = 32; off > 0; off >>= 1) {
        s_iou += __shfl_down(s_iou, off, 64);
        s_cnt += __shfl_down(s_cnt, off, 64);
    }
    __shared__ float lds_iou[THREADS / 64];
    __shared__ float lds_cnt[THREADS / 64];
    int lane = threadIdx.x & 63;
    int wave = threadIdx.x >> 6;
    if (lane == 0) {
        lds_iou[wave] = s_iou;
        lds_cnt[wave] = s_cnt;
    }
    __syncthreads();
    if (threadIdx.x == 0) {
        float a = 0.0f, b = 0.0f;
        #pragma unroll
        for (int w = 0; w < THREADS / 64; ++w) {
            a += lds_iou[w];
            b += lds_cnt[w];
        }
        // final divide runs once; keep it exact
        out[0] = (b > 0.0f) ? (a / fmaxf(b, 1.0f)) : 0.0f;
    }
}

extern "C" void kernel_launch(void* const* d_in, const int* in_sizes, int n_in,
                              void* d_out, int out_size, void* d_ws, size_t ws_size,
                              hipStream_t stream) {
    const float4* pred  = (const float4*)d_in[0];
    const float4* truth = (const float4*)d_in[1];
    float* out = (float*)d_out;
    float* partials = (float*)d_ws;   // BLOCKS*2 floats, overwritten every call

    int n_pairs = in_sizes[0] / 4;    // B * NBOX

    iou_partial<<<BLOCKS, THREADS, 0, stream>>>(pred, truth, partials, n_pairs);
    iou_finalize<<<1, THREADS, 0, stream>>>(partials, BLOCKS, out);
}